// Round 4
// baseline (352.745 us; speedup 1.0000x reference)
//
#include <hip/hip_runtime.h>

// Problem constants (from reference)
#define B_  2
#define N_  20000
#define C_  256
#define K_  5000
#define M_  (B_ * K_)    // 10000
#define MROWS_ 10112     // M padded to multiple of 64 for MFMA tiles (79*128)

#define CAP_ 5376        // survivor capacity per batch (~K + bucket slack)
#define RT_  21          // CAP_/256 j-tiles for rank2
#define RCH_ 7           // rank2 chunk count
#define RCT_ 3           // tiles per rank2 chunk

typedef __attribute__((ext_vector_type(8))) short bf16x8;
typedef __attribute__((ext_vector_type(4))) float f32x4;
typedef __attribute__((ext_vector_type(2))) unsigned long long ull2;

// ---------------------------------------------------------------------------
// bf16 helpers (RNE)
__device__ __forceinline__ unsigned short f2bf(float x) {
  unsigned u = __float_as_uint(x);
  unsigned r = (u + 0x7fffu + ((u >> 16) & 1u)) >> 16;
  return (unsigned short)r;
}
__device__ __forceinline__ float bf2f(unsigned short h) {
  return __uint_as_float(((unsigned)h) << 16);
}

// float -> orderable uint (descending). Scores >= 0 but robust anyway.
__device__ __forceinline__ unsigned fkey(float f) {
  unsigned u = __float_as_uint(f);
  return (u & 0x80000000u) ? ~u : (u | 0x80000000u);
}

// ---------------------------------------------------------------------------
__global__ __launch_bounds__(256) void k_zero(int* __restrict__ p, int n) {
  const int t = blockIdx.x * 256 + threadIdx.x;
  if (t < n) p[t] = 0;
}

// ---------------------------------------------------------------------------
// Two-level radix select: find 22-bit prefix threshold T such that
// #keys with prefix > T  <  K  <=  #keys with prefix >= T.
// One block per batch; 2048-bin LDS histograms on fk[31:21] then fk[20:10].
__global__ __launch_bounds__(1024) void k_sel(const float* __restrict__ score,
                                              int* __restrict__ nc,
                                              unsigned* __restrict__ selT) {
  const int b = blockIdx.x;
  const float* s = score + b * N_;
  __shared__ int h[2048];
  __shared__ int chs[256];
  __shared__ int res[4];  // {b1, cnt_gt1, b2, cnt_gt2}
  const int t = threadIdx.x;
  if (t == 0) nc[b] = 0;
  for (int i = t; i < 2048; i += 1024) h[i] = 0;
  __syncthreads();
  for (int i = t; i < N_; i += 1024) atomicAdd(&h[fkey(s[i]) >> 21], 1);
  __syncthreads();
  int target = K_;
  for (int pass = 0; pass < 2; ++pass) {
    if (t < 256) {
      int sum = 0;
#pragma unroll
      for (int j = 0; j < 8; ++j) sum += h[t * 8 + j];
      chs[t] = sum;
    }
    __syncthreads();
    // inclusive suffix scan over 256 chunk sums
    for (int off = 1; off < 256; off <<= 1) {
      int v = 0;
      if (t < 256) v = chs[t] + ((t + off < 256) ? chs[t + off] : 0);
      __syncthreads();
      if (t < 256) chs[t] = v;
      __syncthreads();
    }
    if (t < 256) {
      const int above = (t + 1 < 256) ? chs[t + 1] : 0;
      if (above < target && target <= chs[t]) {
        int acc = above;
        for (int i = 7; i >= 0; --i) {
          const int bin = t * 8 + i;
          if (acc + h[bin] >= target) { res[pass * 2] = bin; res[pass * 2 + 1] = acc; break; }
          acc += h[bin];
        }
      }
    }
    __syncthreads();
    if (pass == 0) {
      const int b1 = res[0];
      target = K_ - res[1];
      for (int i = t; i < 2048; i += 1024) h[i] = 0;
      __syncthreads();
      for (int i = t; i < N_; i += 1024) {
        const unsigned fk = fkey(s[i]);
        if ((int)(fk >> 21) == b1) atomicAdd(&h[(fk >> 10) & 0x7ffu], 1);
      }
      __syncthreads();
    }
  }
  if (t == 0) selT[b] = (((unsigned)res[0]) << 11) | (unsigned)res[2];
}

// ---------------------------------------------------------------------------
// Compact survivors (prefix >= T) into ck[b][*] as composite u64 keys; also
// default-init rnk[b][n] = K_ for every n.
__global__ __launch_bounds__(256) void k_compact(const float* __restrict__ score,
                                                 const unsigned* __restrict__ selT,
                                                 int* __restrict__ nc,
                                                 unsigned long long* __restrict__ ck,
                                                 int* __restrict__ rnk) {
  const int b = blockIdx.y;
  const int n = blockIdx.x * 256 + threadIdx.x;
  if (n >= N_) return;
  rnk[b * N_ + n] = K_;
  const unsigned fk = fkey(score[b * N_ + n]);
  if ((fk >> 10) >= selT[b]) {
    const int pos = atomicAdd(&nc[b], 1);
    if (pos < CAP_)
      ck[b * CAP_ + pos] = ((unsigned long long)fk << 32) | (unsigned)(N_ - 1 - n);
  }
}

// ---------------------------------------------------------------------------
// Exact rank among survivors (== global rank, survivor set is upward-closed).
__global__ __launch_bounds__(256) void k_rank2(const int* __restrict__ nc,
                                               const unsigned long long* __restrict__ ck,
                                               int* __restrict__ cnt2) {
  const int b = blockIdx.z;
  int S = nc[b]; if (S > CAP_) S = CAP_;
  const int tid = threadIdx.x;
  const int j = blockIdx.x * 256 + tid;
  const unsigned long long* kb = ck + b * CAP_;
  const unsigned long long myk = (j < S) ? kb[j] : 0ULL;
  __shared__ unsigned long long sk[256];
  int c = 0;
  const int nt = (S + 255) >> 8;
  int t0 = blockIdx.y * RCT_, t1 = t0 + RCT_;
  if (t1 > nt) t1 = nt;
  for (int t = t0; t < t1; ++t) {
    const int gi = t * 256 + tid;
    unsigned long long kk = 0ULL;
    if (gi < S) kk = kb[gi];
    __syncthreads();
    sk[tid] = kk;
    __syncthreads();
#pragma unroll 8
    for (int ii = 0; ii < 256; ii += 2) {
      ull2 v = *(const ull2*)&sk[ii];
      c += (int)(v.x > myk);
      c += (int)(v.y > myk);
    }
  }
  if (j < S && c > 0) atomicAdd(&cnt2[b * CAP_ + j], c);
}

// ---------------------------------------------------------------------------
__global__ __launch_bounds__(256) void k_scatter2(const int* __restrict__ nc,
                                                  const unsigned long long* __restrict__ ck,
                                                  const int* __restrict__ cnt2,
                                                  int* __restrict__ keep_i,
                                                  float* __restrict__ keep_f,
                                                  int* __restrict__ rnk) {
  const int b = blockIdx.y;
  int S = nc[b]; if (S > CAP_) S = CAP_;
  const int j = blockIdx.x * 256 + threadIdx.x;
  if (j >= S) return;
  const int r = cnt2[b * CAP_ + j];
  if (r < K_) {
    const int n = N_ - 1 - (int)(ck[b * CAP_ + j] & 0xffffffffu);
    keep_i[b * K_ + r] = n;
    keep_f[b * K_ + r] = (float)n;
    rnk[b * N_ + n] = r;
  }
}

// ---------------------------------------------------------------------------
__global__ __launch_bounds__(256) void k_gatherbox(const int* __restrict__ keep_i,
                                                   const float* __restrict__ box,
                                                   float* __restrict__ boxK,
                                                   unsigned* __restrict__ maxiou) {
  const int t = blockIdx.x * 256 + threadIdx.x;
  if (t >= B_ * K_) return;
  const int b = t / K_;
  const int idx = keep_i[t];
  const float* bb = box + (size_t)b * 4 * N_;
  float4 v;
  v.x = bb[0 * N_ + idx];
  v.y = bb[1 * N_ + idx];
  v.z = bb[2 * N_ + idx];
  v.w = bb[3 * N_ + idx];
  ((float4*)boxK)[t] = v;
  maxiou[t] = 0u;
}

// ---------------------------------------------------------------------------
// max over i<j of IoU(i,j) via atomicMax on float bits. _rn intrinsics keep
// IoU bit-identical to the numpy f32 reference (discrete threshold decisions).
__global__ __launch_bounds__(256) void k_iou(const float* __restrict__ boxK,
                                             unsigned* __restrict__ maxiou) {
  const int jt = blockIdx.x;
  const int it = blockIdx.y;
  if (it > jt) return;
  const int b = blockIdx.z;
  const int tid = threadIdx.x;
  __shared__ float sx0[256], sy0[256], sx1[256], sy1[256], sa[256];
  const int gi0 = it * 256;
  const int gl = gi0 + tid;
  if (gl < K_) {
    float4 v = ((const float4*)boxK)[b * K_ + gl];
    sx0[tid] = v.x; sy0[tid] = v.y; sx1[tid] = v.z; sy1[tid] = v.w;
    sa[tid] = __fmul_rn(__fsub_rn(v.z, v.x), __fsub_rn(v.w, v.y));
  } else {
    sx0[tid] = 1e30f; sy0[tid] = 1e30f; sx1[tid] = -1e30f; sy1[tid] = -1e30f;
    sa[tid] = 0.f;
  }
  __syncthreads();
  const int j = jt * 256 + tid;
  if (j >= K_) return;
  float4 v = ((const float4*)boxK)[b * K_ + j];
  const float aj = __fmul_rn(__fsub_rn(v.z, v.x), __fsub_rn(v.w, v.y));
  float mx = 0.f;
  int lim = j - gi0;
  if (lim > 256) lim = 256;
  for (int ii = 0; ii < lim; ++ii) {
    float ltx = fmaxf(sx0[ii], v.x);
    float lty = fmaxf(sy0[ii], v.y);
    float rbx = fminf(sx1[ii], v.z);
    float rby = fminf(sy1[ii], v.w);
    float wx = fmaxf(__fsub_rn(rbx, ltx), 0.f);
    float wy = fmaxf(__fsub_rn(rby, lty), 0.f);
    float inter = __fmul_rn(wx, wy);
    if (inter > 0.f) {
      float uni = __fsub_rn(__fadd_rn(sa[ii], aj), inter);
      float iou = __fdiv_rn(inter, uni);
      mx = fmaxf(mx, iou);
    }
  }
  if (mx > 0.f) atomicMax(&maxiou[b * K_ + j], __float_as_uint(mx));
}

// ---------------------------------------------------------------------------
// Split W (f32 [6][C][C]) into bf16 hi/lo (same layout).
__global__ __launch_bounds__(256) void k_prepW(const float* __restrict__ W,
                                               unsigned short* __restrict__ Whi,
                                               unsigned short* __restrict__ Wlo) {
  const int t = blockIdx.x * 256 + threadIdx.x;
  if (t >= 6 * C_ * C_) return;
  const float w = W[t];
  const unsigned short h = f2bf(w);
  Whi[t] = h;
  Wlo[t] = f2bf(__fsub_rn(w, bf2f(h)));
}

// ---------------------------------------------------------------------------
// Fused gather+transpose+split: iterate feat in ORIGINAL n order (coalesced
// reads, each element read once), LDS-transpose 64n x 64c tiles, write kept
// rows (rank r) directly to Xt hi/lo [MROWS_][C_].
__global__ __launch_bounds__(256) void k_gathersplit(const int* __restrict__ rnk,
                                                     const float* __restrict__ feat,
                                                     unsigned short* __restrict__ Xhi,
                                                     unsigned short* __restrict__ Xlo) {
  __shared__ float T[64][65];
  const int b = blockIdx.z;
  const int n0 = blockIdx.x * 64;
  const int c0 = blockIdx.y * 64;
  const int t = threadIdx.x;
  const int nl = t & 63;
  const int wq = t >> 6;
#pragma unroll
  for (int r = 0; r < 16; ++r) {
    const int cl = r * 4 + wq;
    const int n = n0 + nl;
    T[nl][cl] = (n < N_) ? feat[((size_t)(b * C_ + c0 + cl)) * N_ + n] : 0.f;
  }
  __syncthreads();
  const int nn = n0 + (t >> 2);
  if (nn >= N_) return;
  const int r = rnk[b * N_ + nn];
  if (r >= K_) return;
  const int cseg = (t & 3) * 16;
  unsigned short hb[16], lb[16];
#pragma unroll
  for (int i = 0; i < 16; ++i) {
    const float v = T[t >> 2][cseg + i];
    const unsigned short h = f2bf(v);
    hb[i] = h;
    lb[i] = f2bf(__fsub_rn(v, bf2f(h)));
  }
  const size_t base = (size_t)(b * K_ + r) * C_ + c0 + cseg;
  *(uint4*)&Xhi[base]     = *(const uint4*)&hb[0];
  *(uint4*)&Xhi[base + 8] = *(const uint4*)&hb[8];
  *(uint4*)&Xlo[base]     = *(const uint4*)&lb[0];
  *(uint4*)&Xlo[base + 8] = *(const uint4*)&lb[8];
}

// ---------------------------------------------------------------------------
// MLP layer, barrier-free main loop: fragments straight from global (L1/L2).
// Block = 64m x 64o, 4 waves (2x2), per-wave 32m x 32o (2x2 MFMA tiles,
// 3 split terms). Epilogue: bias+leaky -> LDS transpose -> bf16 hi/lo store.
__global__ __launch_bounds__(256) void k_mlp(const unsigned short* __restrict__ Whi,
                                             const unsigned short* __restrict__ Wlo,
                                             const float* __restrict__ bias,
                                             const unsigned short* __restrict__ Xhi,
                                             const unsigned short* __restrict__ Xlo,
                                             unsigned short* __restrict__ Yhi,
                                             unsigned short* __restrict__ Ylo) {
  __shared__ float Yt[64][68];
  const int m0 = blockIdx.x * 64;
  const int o0 = blockIdx.y * 64;
  const int t = threadIdx.x;
  const int lane = t & 63;
  const int w = t >> 6;
  const int wm = w & 1, wo = w >> 1;
  const int quad = lane >> 4, l15 = lane & 15;

  const size_t a0 = (size_t)(m0 + wm * 32 + l15) * C_ + quad * 8;
  const size_t a1 = a0 + (size_t)16 * C_;
  const size_t br0 = (size_t)(o0 + wo * 32 + l15) * C_ + quad * 8;
  const size_t br1 = br0 + (size_t)16 * C_;

  f32x4 acc[2][2];
#pragma unroll
  for (int mi = 0; mi < 2; ++mi)
#pragma unroll
    for (int oi = 0; oi < 2; ++oi) acc[mi][oi] = (f32x4)0.f;

#pragma unroll 4
  for (int ks = 0; ks < 8; ++ks) {
    const int k = ks * 32;
    const bf16x8 Ah0 = *(const bf16x8*)&Xhi[a0 + k];
    const bf16x8 Ah1 = *(const bf16x8*)&Xhi[a1 + k];
    const bf16x8 Al0 = *(const bf16x8*)&Xlo[a0 + k];
    const bf16x8 Al1 = *(const bf16x8*)&Xlo[a1 + k];
    const bf16x8 Bh0 = *(const bf16x8*)&Whi[br0 + k];
    const bf16x8 Bh1 = *(const bf16x8*)&Whi[br1 + k];
    const bf16x8 Bl0 = *(const bf16x8*)&Wlo[br0 + k];
    const bf16x8 Bl1 = *(const bf16x8*)&Wlo[br1 + k];
    acc[0][0] = __builtin_amdgcn_mfma_f32_16x16x32_bf16(Ah0, Bh0, acc[0][0], 0, 0, 0);
    acc[0][0] = __builtin_amdgcn_mfma_f32_16x16x32_bf16(Ah0, Bl0, acc[0][0], 0, 0, 0);
    acc[0][0] = __builtin_amdgcn_mfma_f32_16x16x32_bf16(Al0, Bh0, acc[0][0], 0, 0, 0);
    acc[0][1] = __builtin_amdgcn_mfma_f32_16x16x32_bf16(Ah0, Bh1, acc[0][1], 0, 0, 0);
    acc[0][1] = __builtin_amdgcn_mfma_f32_16x16x32_bf16(Ah0, Bl1, acc[0][1], 0, 0, 0);
    acc[0][1] = __builtin_amdgcn_mfma_f32_16x16x32_bf16(Al0, Bh1, acc[0][1], 0, 0, 0);
    acc[1][0] = __builtin_amdgcn_mfma_f32_16x16x32_bf16(Ah1, Bh0, acc[1][0], 0, 0, 0);
    acc[1][0] = __builtin_amdgcn_mfma_f32_16x16x32_bf16(Ah1, Bl0, acc[1][0], 0, 0, 0);
    acc[1][0] = __builtin_amdgcn_mfma_f32_16x16x32_bf16(Al1, Bh0, acc[1][0], 0, 0, 0);
    acc[1][1] = __builtin_amdgcn_mfma_f32_16x16x32_bf16(Ah1, Bh1, acc[1][1], 0, 0, 0);
    acc[1][1] = __builtin_amdgcn_mfma_f32_16x16x32_bf16(Ah1, Bl1, acc[1][1], 0, 0, 0);
    acc[1][1] = __builtin_amdgcn_mfma_f32_16x16x32_bf16(Al1, Bh1, acc[1][1], 0, 0, 0);
  }
  const float bv0 = bias[o0 + wo * 32 + l15];
  const float bv1 = bias[o0 + wo * 32 + 16 + l15];
#pragma unroll
  for (int mi = 0; mi < 2; ++mi)
#pragma unroll
    for (int oi = 0; oi < 2; ++oi) {
      const float bb = oi ? bv1 : bv0;
#pragma unroll
      for (int r = 0; r < 4; ++r) {
        float y = acc[mi][oi][r] + bb;
        y = fmaxf(y, 0.2f * y);
        Yt[wm * 32 + mi * 16 + quad * 4 + r][wo * 32 + oi * 16 + l15] = y;
      }
    }
  __syncthreads();
  const int row = t >> 2;
  const int cseg = (t & 3) * 16;
  unsigned short hb[16], lb[16];
#pragma unroll
  for (int i = 0; i < 16; ++i) {
    const float v = Yt[row][cseg + i];
    const unsigned short h = f2bf(v);
    hb[i] = h;
    lb[i] = f2bf(__fsub_rn(v, bf2f(h)));
  }
  const size_t base = (size_t)(m0 + row) * C_ + o0 + cseg;
  *(uint4*)&Yhi[base]     = *(const uint4*)&hb[0];
  *(uint4*)&Yhi[base + 8] = *(const uint4*)&hb[8];
  *(uint4*)&Ylo[base]     = *(const uint4*)&lb[0];
  *(uint4*)&Ylo[base + 8] = *(const uint4*)&lb[8];
}

// ---------------------------------------------------------------------------
// Final: logits = Wf @ x + bf (3 rows), softmax over 3, masked sum by max-iou.
__global__ __launch_bounds__(256) void k_final(const unsigned short* __restrict__ Xhi,
                                               const unsigned short* __restrict__ Xlo,
                                               const float* __restrict__ Wf,
                                               const float* __restrict__ bf,
                                               const unsigned* __restrict__ maxiou,
                                               float* __restrict__ out_loc) {
  __shared__ float sw[3 * 256];
  const int tid = threadIdx.x;
  sw[tid] = Wf[tid];
  sw[256 + tid] = Wf[256 + tid];
  sw[512 + tid] = Wf[512 + tid];
  __syncthreads();
  const int m = blockIdx.x * 256 + tid;
  if (m >= M_) return;
  float a0 = 0.f, a1 = 0.f, a2 = 0.f;
  const unsigned short* xh = Xhi + (size_t)m * C_;
  const unsigned short* xl = Xlo + (size_t)m * C_;
#pragma unroll 4
  for (int c = 0; c < C_; c += 8) {
    uint4 hv = *(const uint4*)&xh[c];
    uint4 lv = *(const uint4*)&xl[c];
    const unsigned hw[4] = {hv.x, hv.y, hv.z, hv.w};
    const unsigned lw[4] = {lv.x, lv.y, lv.z, lv.w};
#pragma unroll
    for (int q = 0; q < 4; ++q) {
      const float x0 = __uint_as_float((hw[q] & 0xffffu) << 16) +
                       __uint_as_float((lw[q] & 0xffffu) << 16);
      const float x1 = __uint_as_float(hw[q] & 0xffff0000u) +
                       __uint_as_float(lw[q] & 0xffff0000u);
      const int cc = c + q * 2;
      a0 += sw[cc] * x0 + sw[cc + 1] * x1;
      a1 += sw[256 + cc] * x0 + sw[256 + cc + 1] * x1;
      a2 += sw[512 + cc] * x0 + sw[512 + cc + 1] * x1;
    }
  }
  a0 += bf[0]; a1 += bf[1]; a2 += bf[2];
  const float mxv = fmaxf(a0, fmaxf(a1, a2));
  const float e0 = expf(a0 - mxv);
  const float e1 = expf(a1 - mxv);
  const float e2 = expf(a2 - mxv);
  const float inv = 1.f / (e0 + e1 + e2);
  const float miou = __uint_as_float(maxiou[m]);
  float loc = 0.f;
  if (miou < 0.4f) loc += e0;
  if (miou < 0.6f) loc += e1;
  if (miou < 0.8f) loc += e2;
  out_loc[m] = loc * inv;
}

// ---------------------------------------------------------------------------
extern "C" void kernel_launch(void* const* d_in, const int* in_sizes, int n_in,
                              void* d_out, int out_size, void* d_ws, size_t ws_size,
                              hipStream_t stream) {
  const float* box   = (const float*)d_in[0];
  const float* score = (const float*)d_in[1];
  const float* feat  = (const float*)d_in[2];
  const float* W     = (const float*)d_in[3];
  const float* bias  = (const float*)d_in[4];
  const float* Wf    = (const float*)d_in[5];
  const float* bf    = (const float*)d_in[6];

  float* out = (float*)d_out;
  float* out_loc  = out;        // [B*K]
  float* out_keep = out + M_;   // [B*K] keep as float

  // Workspace layout (total 22,523,904 B <= proven-OK 22.8 MB)
  char* ws = (char*)d_ws;
  int*            keep_i = (int*)(ws + 0);                    // 40000
  float*          boxK   = (float*)(ws + 40960);              // 160000
  unsigned*       maxiou = (unsigned*)(ws + 201216);          // 40000
  unsigned short* Whi    = (unsigned short*)(ws + 241664);    // 786432
  unsigned short* Wlo    = (unsigned short*)(ws + 1028096);   // 786432
  unsigned short* XtA_hi = (unsigned short*)(ws + 1814528);   // 5177344
  unsigned short* XtA_lo = (unsigned short*)(ws + 6991872);   // 5177344
  unsigned short* XtB_hi = (unsigned short*)(ws + 12169216);  // 5177344
  unsigned short* XtB_lo = (unsigned short*)(ws + 17346560);  // 5177344
  // Select-path scratch aliases XtB (dead before k_mlp layer 0 writes XtB):
  int*                rnk  = (int*)(ws + 12169216);                 // 160000
  unsigned long long* ck   = (unsigned long long*)(ws + 12329216);  // 86016
  int*                cnt2 = (int*)(ws + 12415232);                 // 43008
  int*                nc   = (int*)(ws + 12458240);                 // 8
  unsigned*           selT = (unsigned*)(ws + 12458304);            // 8

  k_prepW<<<(6 * C_ * C_ + 255) / 256, 256, 0, stream>>>(W, Whi, Wlo);
  k_sel<<<B_, 1024, 0, stream>>>(score, nc, selT);
  k_zero<<<(B_ * CAP_ + 255) / 256, 256, 0, stream>>>(cnt2, B_ * CAP_);
  k_compact<<<dim3((N_ + 255) / 256, B_), 256, 0, stream>>>(score, selT, nc, ck, rnk);
  k_rank2<<<dim3(RT_, RCH_, B_), 256, 0, stream>>>(nc, ck, cnt2);
  k_scatter2<<<dim3(RT_, B_), 256, 0, stream>>>(nc, ck, cnt2, keep_i, out_keep, rnk);
  k_gatherbox<<<(B_ * K_ + 255) / 256, 256, 0, stream>>>(keep_i, box, boxK, maxiou);
  k_iou<<<dim3((K_ + 255) / 256, (K_ + 255) / 256, B_), 256, 0, stream>>>(boxK, maxiou);
  k_gathersplit<<<dim3((N_ + 63) / 64, C_ / 64, B_), 256, 0, stream>>>(rnk, feat, XtA_hi, XtA_lo);

  const unsigned short* xih = XtA_hi; const unsigned short* xil = XtA_lo;
  unsigned short* xoh = XtB_hi;       unsigned short* xol = XtB_lo;
  for (int l = 0; l < 6; ++l) {
    k_mlp<<<dim3(MROWS_ / 64, C_ / 64), 256, 0, stream>>>(
        Whi + (size_t)l * C_ * C_, Wlo + (size_t)l * C_ * C_,
        bias + (size_t)l * C_, xih, xil, xoh, xol);
    const unsigned short* th = xoh; const unsigned short* tl = xol;
    xoh = (unsigned short*)xih; xol = (unsigned short*)xil;
    xih = th; xil = tl;
  }
  // after 6 layers activations are in XtA (xih/xil point at it)

  k_final<<<(M_ + 255) / 256, 256, 0, stream>>>(xih, xil, Wf, bf, maxiou, out_loc);
}

// Round 5
// 290.702 us; speedup vs baseline: 1.2134x; 1.2134x over previous
//
#include <hip/hip_runtime.h>

// Problem constants (from reference)
#define B_  2
#define N_  20000
#define C_  256
#define K_  5000
#define M_  (B_ * K_)    // 10000
#define MROWS_ 10112     // M padded to multiple of 128 for MFMA tiles (79*128)

#define CAP_ 5376        // survivor capacity per batch (~K + bucket slack)
#define RT_  21          // CAP_/256 j-tiles for rank2
#define RCH_ 7           // rank2 chunk count
#define RCT_ 3           // tiles per rank2 chunk

typedef __attribute__((ext_vector_type(8))) short bf16x8;
typedef __attribute__((ext_vector_type(4))) float f32x4;
typedef __attribute__((ext_vector_type(2))) unsigned long long ull2;

// ---------------------------------------------------------------------------
// bf16 helpers (RNE)
__device__ __forceinline__ unsigned short f2bf(float x) {
  unsigned u = __float_as_uint(x);
  unsigned r = (u + 0x7fffu + ((u >> 16) & 1u)) >> 16;
  return (unsigned short)r;
}
__device__ __forceinline__ float bf2f(unsigned short h) {
  return __uint_as_float(((unsigned)h) << 16);
}

// float -> orderable uint (descending). Scores >= 0 but robust anyway.
__device__ __forceinline__ unsigned fkey(float f) {
  unsigned u = __float_as_uint(f);
  return (u & 0x80000000u) ? ~u : (u | 0x80000000u);
}

// ---------------------------------------------------------------------------
__global__ __launch_bounds__(256) void k_zero(int* __restrict__ p, int n) {
  const int t = blockIdx.x * 256 + threadIdx.x;
  if (t < n) p[t] = 0;
}

// ---------------------------------------------------------------------------
// Two-level radix select: find 22-bit prefix threshold T such that
// #keys with prefix > T  <  K  <=  #keys with prefix >= T.
// One block per batch; 2048-bin LDS histograms on fk[31:21] then fk[20:10].
__global__ __launch_bounds__(1024) void k_sel(const float* __restrict__ score,
                                              int* __restrict__ nc,
                                              unsigned* __restrict__ selT) {
  const int b = blockIdx.x;
  const float* s = score + b * N_;
  __shared__ int h[2048];
  __shared__ int chs[256];
  __shared__ int res[4];  // {b1, cnt_gt1, b2, cnt_gt2}
  const int t = threadIdx.x;
  if (t == 0) nc[b] = 0;
  for (int i = t; i < 2048; i += 1024) h[i] = 0;
  __syncthreads();
  for (int i = t; i < N_; i += 1024) atomicAdd(&h[fkey(s[i]) >> 21], 1);
  __syncthreads();
  int target = K_;
  for (int pass = 0; pass < 2; ++pass) {
    if (t < 256) {
      int sum = 0;
#pragma unroll
      for (int j = 0; j < 8; ++j) sum += h[t * 8 + j];
      chs[t] = sum;
    }
    __syncthreads();
    // inclusive suffix scan over 256 chunk sums
    for (int off = 1; off < 256; off <<= 1) {
      int v = 0;
      if (t < 256) v = chs[t] + ((t + off < 256) ? chs[t + off] : 0);
      __syncthreads();
      if (t < 256) chs[t] = v;
      __syncthreads();
    }
    if (t < 256) {
      const int above = (t + 1 < 256) ? chs[t + 1] : 0;
      if (above < target && target <= chs[t]) {
        int acc = above;
        for (int i = 7; i >= 0; --i) {
          const int bin = t * 8 + i;
          if (acc + h[bin] >= target) { res[pass * 2] = bin; res[pass * 2 + 1] = acc; break; }
          acc += h[bin];
        }
      }
    }
    __syncthreads();
    if (pass == 0) {
      const int b1 = res[0];
      target = K_ - res[1];
      for (int i = t; i < 2048; i += 1024) h[i] = 0;
      __syncthreads();
      for (int i = t; i < N_; i += 1024) {
        const unsigned fk = fkey(s[i]);
        if ((int)(fk >> 21) == b1) atomicAdd(&h[(fk >> 10) & 0x7ffu], 1);
      }
      __syncthreads();
    }
  }
  if (t == 0) selT[b] = (((unsigned)res[0]) << 11) | (unsigned)res[2];
}

// ---------------------------------------------------------------------------
// Compact survivors (prefix >= T) into ck[b][*] as composite u64 keys; also
// default-init rnk[b][n] = K_ for every n.
__global__ __launch_bounds__(256) void k_compact(const float* __restrict__ score,
                                                 const unsigned* __restrict__ selT,
                                                 int* __restrict__ nc,
                                                 unsigned long long* __restrict__ ck,
                                                 int* __restrict__ rnk) {
  const int b = blockIdx.y;
  const int n = blockIdx.x * 256 + threadIdx.x;
  if (n >= N_) return;
  rnk[b * N_ + n] = K_;
  const unsigned fk = fkey(score[b * N_ + n]);
  if ((fk >> 10) >= selT[b]) {
    const int pos = atomicAdd(&nc[b], 1);
    if (pos < CAP_)
      ck[b * CAP_ + pos] = ((unsigned long long)fk << 32) | (unsigned)(N_ - 1 - n);
  }
}

// ---------------------------------------------------------------------------
// Exact rank among survivors (== global rank, survivor set is upward-closed).
__global__ __launch_bounds__(256) void k_rank2(const int* __restrict__ nc,
                                               const unsigned long long* __restrict__ ck,
                                               int* __restrict__ cnt2) {
  const int b = blockIdx.z;
  int S = nc[b]; if (S > CAP_) S = CAP_;
  const int tid = threadIdx.x;
  const int j = blockIdx.x * 256 + tid;
  const unsigned long long* kb = ck + b * CAP_;
  const unsigned long long myk = (j < S) ? kb[j] : 0ULL;
  __shared__ unsigned long long sk[256];
  int c = 0;
  const int nt = (S + 255) >> 8;
  int t0 = blockIdx.y * RCT_, t1 = t0 + RCT_;
  if (t1 > nt) t1 = nt;
  for (int t = t0; t < t1; ++t) {
    const int gi = t * 256 + tid;
    unsigned long long kk = 0ULL;
    if (gi < S) kk = kb[gi];
    __syncthreads();
    sk[tid] = kk;
    __syncthreads();
#pragma unroll 8
    for (int ii = 0; ii < 256; ii += 2) {
      ull2 v = *(const ull2*)&sk[ii];
      c += (int)(v.x > myk);
      c += (int)(v.y > myk);
    }
  }
  if (j < S && c > 0) atomicAdd(&cnt2[b * CAP_ + j], c);
}

// ---------------------------------------------------------------------------
__global__ __launch_bounds__(256) void k_scatter2(const int* __restrict__ nc,
                                                  const unsigned long long* __restrict__ ck,
                                                  const int* __restrict__ cnt2,
                                                  int* __restrict__ keep_i,
                                                  float* __restrict__ keep_f,
                                                  int* __restrict__ rnk) {
  const int b = blockIdx.y;
  int S = nc[b]; if (S > CAP_) S = CAP_;
  const int j = blockIdx.x * 256 + threadIdx.x;
  if (j >= S) return;
  const int r = cnt2[b * CAP_ + j];
  if (r < K_) {
    const int n = N_ - 1 - (int)(ck[b * CAP_ + j] & 0xffffffffu);
    keep_i[b * K_ + r] = n;
    keep_f[b * K_ + r] = (float)n;
    rnk[b * N_ + n] = r;
  }
}

// ---------------------------------------------------------------------------
__global__ __launch_bounds__(256) void k_gatherbox(const int* __restrict__ keep_i,
                                                   const float* __restrict__ box,
                                                   float* __restrict__ boxK,
                                                   unsigned* __restrict__ maxiou) {
  const int t = blockIdx.x * 256 + threadIdx.x;
  if (t >= B_ * K_) return;
  const int b = t / K_;
  const int idx = keep_i[t];
  const float* bb = box + (size_t)b * 4 * N_;
  float4 v;
  v.x = bb[0 * N_ + idx];
  v.y = bb[1 * N_ + idx];
  v.z = bb[2 * N_ + idx];
  v.w = bb[3 * N_ + idx];
  ((float4*)boxK)[t] = v;
  maxiou[t] = 0u;
}

// ---------------------------------------------------------------------------
// max over i<j of IoU(i,j) via atomicMax on float bits. _rn intrinsics keep
// IoU bit-identical to the numpy f32 reference (discrete threshold decisions).
__global__ __launch_bounds__(256) void k_iou(const float* __restrict__ boxK,
                                             unsigned* __restrict__ maxiou) {
  const int jt = blockIdx.x;
  const int it = blockIdx.y;
  if (it > jt) return;
  const int b = blockIdx.z;
  const int tid = threadIdx.x;
  __shared__ float sx0[256], sy0[256], sx1[256], sy1[256], sa[256];
  const int gi0 = it * 256;
  const int gl = gi0 + tid;
  if (gl < K_) {
    float4 v = ((const float4*)boxK)[b * K_ + gl];
    sx0[tid] = v.x; sy0[tid] = v.y; sx1[tid] = v.z; sy1[tid] = v.w;
    sa[tid] = __fmul_rn(__fsub_rn(v.z, v.x), __fsub_rn(v.w, v.y));
  } else {
    sx0[tid] = 1e30f; sy0[tid] = 1e30f; sx1[tid] = -1e30f; sy1[tid] = -1e30f;
    sa[tid] = 0.f;
  }
  __syncthreads();
  const int j = jt * 256 + tid;
  if (j >= K_) return;
  float4 v = ((const float4*)boxK)[b * K_ + j];
  const float aj = __fmul_rn(__fsub_rn(v.z, v.x), __fsub_rn(v.w, v.y));
  float mx = 0.f;
  int lim = j - gi0;
  if (lim > 256) lim = 256;
  for (int ii = 0; ii < lim; ++ii) {
    float ltx = fmaxf(sx0[ii], v.x);
    float lty = fmaxf(sy0[ii], v.y);
    float rbx = fminf(sx1[ii], v.z);
    float rby = fminf(sy1[ii], v.w);
    float wx = fmaxf(__fsub_rn(rbx, ltx), 0.f);
    float wy = fmaxf(__fsub_rn(rby, lty), 0.f);
    float inter = __fmul_rn(wx, wy);
    if (inter > 0.f) {
      float uni = __fsub_rn(__fadd_rn(sa[ii], aj), inter);
      float iou = __fdiv_rn(inter, uni);
      mx = fmaxf(mx, iou);
    }
  }
  if (mx > 0.f) atomicMax(&maxiou[b * K_ + j], __float_as_uint(mx));
}

// ---------------------------------------------------------------------------
// Split W (f32 [6][C][C]) into bf16 hi/lo (same layout).
__global__ __launch_bounds__(256) void k_prepW(const float* __restrict__ W,
                                               unsigned short* __restrict__ Whi,
                                               unsigned short* __restrict__ Wlo) {
  const int t = blockIdx.x * 256 + threadIdx.x;
  if (t >= 6 * C_ * C_) return;
  const float w = W[t];
  const unsigned short h = f2bf(w);
  Whi[t] = h;
  Wlo[t] = f2bf(__fsub_rn(w, bf2f(h)));
}

// ---------------------------------------------------------------------------
// Fused gather+transpose+split: iterate feat in ORIGINAL n order (coalesced
// reads, each element read once), LDS-transpose 64n x 64c tiles, write kept
// rows (rank r) directly to Xt hi/lo [MROWS_][C_].
__global__ __launch_bounds__(256) void k_gathersplit(const int* __restrict__ rnk,
                                                     const float* __restrict__ feat,
                                                     unsigned short* __restrict__ Xhi,
                                                     unsigned short* __restrict__ Xlo) {
  __shared__ float T[64][65];
  const int b = blockIdx.z;
  const int n0 = blockIdx.x * 64;
  const int c0 = blockIdx.y * 64;
  const int t = threadIdx.x;
  const int nl = t & 63;
  const int wq = t >> 6;
#pragma unroll
  for (int r = 0; r < 16; ++r) {
    const int cl = r * 4 + wq;
    const int n = n0 + nl;
    T[nl][cl] = (n < N_) ? feat[((size_t)(b * C_ + c0 + cl)) * N_ + n] : 0.f;
  }
  __syncthreads();
  const int nn = n0 + (t >> 2);
  if (nn >= N_) return;
  const int r = rnk[b * N_ + nn];
  if (r >= K_) return;
  const int cseg = (t & 3) * 16;
  unsigned short hb[16], lb[16];
#pragma unroll
  for (int i = 0; i < 16; ++i) {
    const float v = T[t >> 2][cseg + i];
    const unsigned short h = f2bf(v);
    hb[i] = h;
    lb[i] = f2bf(__fsub_rn(v, bf2f(h)));
  }
  const size_t base = (size_t)(b * K_ + r) * C_ + c0 + cseg;
  *(uint4*)&Xhi[base]     = *(const uint4*)&hb[0];
  *(uint4*)&Xhi[base + 8] = *(const uint4*)&hb[8];
  *(uint4*)&Xlo[base]     = *(const uint4*)&lb[0];
  *(uint4*)&Xlo[base + 8] = *(const uint4*)&lb[8];
}

// ---------------------------------------------------------------------------
// MLP layer (R3-proven LDS-staged version): Y[m][o] = leaky_relu(Xt·W^T + b),
// output bf16 hi/lo in Xt layout [MROWS_][C]. Split-bf16 3-term MFMA.
// Block tile 128m x 64o, 4 waves (2x2), per-wave 64m x 32o = 4x2 MFMA tiles.
#define LDSTRIDE 40  // shorts per 32-k row: 16B aligned, 2-way banks (free)
__global__ __launch_bounds__(256) void k_mlp(const unsigned short* __restrict__ Whi,
                                             const unsigned short* __restrict__ Wlo,
                                             const float* __restrict__ bias,
                                             const unsigned short* __restrict__ Xhi,
                                             const unsigned short* __restrict__ Xlo,
                                             unsigned short* __restrict__ Yhi,
                                             unsigned short* __restrict__ Ylo) {
  __shared__ char arena[128 * 68 * 4];  // 34816 B; staging needs 30720 B
  unsigned short* Xs_hi = (unsigned short*)arena;        // [128][40]
  unsigned short* Xs_lo = Xs_hi + 128 * LDSTRIDE;
  unsigned short* Ws_hi = Xs_lo + 128 * LDSTRIDE;        // [64][40]
  unsigned short* Ws_lo = Ws_hi + 64 * LDSTRIDE;
  float* Yt = (float*)arena;                             // [128][68] (reuse)

  const int m0 = blockIdx.x * 128;
  const int o0 = blockIdx.y * 64;
  const int t = threadIdx.x;
  const int lane = t & 63;
  const int wave = t >> 6;
  const int wm = wave & 1;      // m half (64)
  const int wo = wave >> 1;     // o half (32)
  const int quad = lane >> 4;
  const int l15 = lane & 15;

  // staging map: X segs 512/array -> rows t>>2 and 64+(t>>2), quad t&3
  const int xr = t >> 2, xq = (t & 3) * 8;

  f32x4 acc[4][2];
#pragma unroll
  for (int mi = 0; mi < 4; ++mi)
#pragma unroll
    for (int oi = 0; oi < 2; ++oi) acc[mi][oi] = (f32x4)0.f;

  uint4 sxh0, sxh1, sxl0, sxl1, swh, swl;
  // preload k-step 0
  {
    const int k0 = 0;
    sxh0 = *(const uint4*)&Xhi[(size_t)(m0 + xr) * C_ + k0 + xq];
    sxh1 = *(const uint4*)&Xhi[(size_t)(m0 + xr + 64) * C_ + k0 + xq];
    sxl0 = *(const uint4*)&Xlo[(size_t)(m0 + xr) * C_ + k0 + xq];
    sxl1 = *(const uint4*)&Xlo[(size_t)(m0 + xr + 64) * C_ + k0 + xq];
    swh  = *(const uint4*)&Whi[(size_t)(o0 + xr) * C_ + k0 + xq];
    swl  = *(const uint4*)&Wlo[(size_t)(o0 + xr) * C_ + k0 + xq];
  }
#pragma unroll
  for (int ks = 0; ks < 8; ++ks) {
    __syncthreads();  // previous iteration's frag reads complete
    *(uint4*)&Xs_hi[xr * LDSTRIDE + xq] = sxh0;
    *(uint4*)&Xs_hi[(xr + 64) * LDSTRIDE + xq] = sxh1;
    *(uint4*)&Xs_lo[xr * LDSTRIDE + xq] = sxl0;
    *(uint4*)&Xs_lo[(xr + 64) * LDSTRIDE + xq] = sxl1;
    *(uint4*)&Ws_hi[xr * LDSTRIDE + xq] = swh;
    *(uint4*)&Ws_lo[xr * LDSTRIDE + xq] = swl;
    __syncthreads();
    if (ks < 7) {  // prefetch next k-step while MFMA phase runs
      const int k1 = (ks + 1) * 32;
      sxh0 = *(const uint4*)&Xhi[(size_t)(m0 + xr) * C_ + k1 + xq];
      sxh1 = *(const uint4*)&Xhi[(size_t)(m0 + xr + 64) * C_ + k1 + xq];
      sxl0 = *(const uint4*)&Xlo[(size_t)(m0 + xr) * C_ + k1 + xq];
      sxl1 = *(const uint4*)&Xlo[(size_t)(m0 + xr + 64) * C_ + k1 + xq];
      swh  = *(const uint4*)&Whi[(size_t)(o0 + xr) * C_ + k1 + xq];
      swl  = *(const uint4*)&Wlo[(size_t)(o0 + xr) * C_ + k1 + xq];
    }
    bf16x8 Ah[4], Al[4], Bh[2], Bl[2];
#pragma unroll
    for (int mi = 0; mi < 4; ++mi) {
      const int row = (wm * 64 + mi * 16 + l15) * LDSTRIDE + quad * 8;
      Ah[mi] = *(const bf16x8*)&Xs_hi[row];
      Al[mi] = *(const bf16x8*)&Xs_lo[row];
    }
#pragma unroll
    for (int oi = 0; oi < 2; ++oi) {
      const int row = (wo * 32 + oi * 16 + l15) * LDSTRIDE + quad * 8;
      Bh[oi] = *(const bf16x8*)&Ws_hi[row];
      Bl[oi] = *(const bf16x8*)&Ws_lo[row];
    }
#pragma unroll
    for (int mi = 0; mi < 4; ++mi)
#pragma unroll
      for (int oi = 0; oi < 2; ++oi) {
        acc[mi][oi] = __builtin_amdgcn_mfma_f32_16x16x32_bf16(Ah[mi], Bh[oi], acc[mi][oi], 0, 0, 0);
        acc[mi][oi] = __builtin_amdgcn_mfma_f32_16x16x32_bf16(Ah[mi], Bl[oi], acc[mi][oi], 0, 0, 0);
        acc[mi][oi] = __builtin_amdgcn_mfma_f32_16x16x32_bf16(Al[mi], Bh[oi], acc[mi][oi], 0, 0, 0);
      }
  }
  // epilogue: bias + leaky, stash f32 tile in LDS, then coalesced hi/lo store
  const float b0 = bias[o0 + wo * 32 + l15];
  const float b1 = bias[o0 + wo * 32 + 16 + l15];
  __syncthreads();  // done with staging LDS; reuse as Yt
#pragma unroll
  for (int mi = 0; mi < 4; ++mi)
#pragma unroll
    for (int oi = 0; oi < 2; ++oi) {
      const float bb = oi ? b1 : b0;
#pragma unroll
      for (int r = 0; r < 4; ++r) {
        float y = acc[mi][oi][r] + bb;
        y = fmaxf(y, 0.2f * y);
        Yt[(wm * 64 + mi * 16 + quad * 4 + r) * 68 + wo * 32 + oi * 16 + l15] = y;
      }
    }
  __syncthreads();
  const int ml = t & 127, oh = t >> 7;  // thread: row ml, o-half oh (32 wide)
  unsigned short hbuf[32], lbuf[32];
#pragma unroll
  for (int i = 0; i < 32; i += 4) {
    f32x4 v = *(const f32x4*)&Yt[ml * 68 + oh * 32 + i];
#pragma unroll
    for (int jj = 0; jj < 4; ++jj) {
      const unsigned short h = f2bf(v[jj]);
      hbuf[i + jj] = h;
      lbuf[i + jj] = f2bf(__fsub_rn(v[jj], bf2f(h)));
    }
  }
  const size_t obase = (size_t)(m0 + ml) * C_ + o0 + oh * 32;
#pragma unroll
  for (int i = 0; i < 32; i += 8) {
    *(uint4*)&Yhi[obase + i] = *(const uint4*)&hbuf[i];
    *(uint4*)&Ylo[obase + i] = *(const uint4*)&lbuf[i];
  }
}

// ---------------------------------------------------------------------------
// Final: logits = Wf @ x + bf (3 rows), softmax over 3, masked sum by max-iou.
__global__ __launch_bounds__(256) void k_final(const unsigned short* __restrict__ Xhi,
                                               const unsigned short* __restrict__ Xlo,
                                               const float* __restrict__ Wf,
                                               const float* __restrict__ bf,
                                               const unsigned* __restrict__ maxiou,
                                               float* __restrict__ out_loc) {
  __shared__ float sw[3 * 256];
  const int tid = threadIdx.x;
  sw[tid] = Wf[tid];
  sw[256 + tid] = Wf[256 + tid];
  sw[512 + tid] = Wf[512 + tid];
  __syncthreads();
  const int m = blockIdx.x * 256 + tid;
  if (m >= M_) return;
  float a0 = 0.f, a1 = 0.f, a2 = 0.f;
  const unsigned short* xh = Xhi + (size_t)m * C_;
  const unsigned short* xl = Xlo + (size_t)m * C_;
#pragma unroll 4
  for (int c = 0; c < C_; c += 8) {
    uint4 hv = *(const uint4*)&xh[c];
    uint4 lv = *(const uint4*)&xl[c];
    const unsigned hw[4] = {hv.x, hv.y, hv.z, hv.w};
    const unsigned lw[4] = {lv.x, lv.y, lv.z, lv.w};
#pragma unroll
    for (int q = 0; q < 4; ++q) {
      const float x0 = __uint_as_float((hw[q] & 0xffffu) << 16) +
                       __uint_as_float((lw[q] & 0xffffu) << 16);
      const float x1 = __uint_as_float(hw[q] & 0xffff0000u) +
                       __uint_as_float(lw[q] & 0xffff0000u);
      const int cc = c + q * 2;
      a0 += sw[cc] * x0 + sw[cc + 1] * x1;
      a1 += sw[256 + cc] * x0 + sw[256 + cc + 1] * x1;
      a2 += sw[512 + cc] * x0 + sw[512 + cc + 1] * x1;
    }
  }
  a0 += bf[0]; a1 += bf[1]; a2 += bf[2];
  const float mxv = fmaxf(a0, fmaxf(a1, a2));
  const float e0 = expf(a0 - mxv);
  const float e1 = expf(a1 - mxv);
  const float e2 = expf(a2 - mxv);
  const float inv = 1.f / (e0 + e1 + e2);
  const float miou = __uint_as_float(maxiou[m]);
  float loc = 0.f;
  if (miou < 0.4f) loc += e0;
  if (miou < 0.6f) loc += e1;
  if (miou < 0.8f) loc += e2;
  out_loc[m] = loc * inv;
}

// ---------------------------------------------------------------------------
extern "C" void kernel_launch(void* const* d_in, const int* in_sizes, int n_in,
                              void* d_out, int out_size, void* d_ws, size_t ws_size,
                              hipStream_t stream) {
  const float* box   = (const float*)d_in[0];
  const float* score = (const float*)d_in[1];
  const float* feat  = (const float*)d_in[2];
  const float* W     = (const float*)d_in[3];
  const float* bias  = (const float*)d_in[4];
  const float* Wf    = (const float*)d_in[5];
  const float* bf    = (const float*)d_in[6];

  float* out = (float*)d_out;
  float* out_loc  = out;        // [B*K]
  float* out_keep = out + M_;   // [B*K] keep as float

  // Workspace layout (total 22,523,904 B)
  char* ws = (char*)d_ws;
  int*            keep_i = (int*)(ws + 0);                    // 40000
  float*          boxK   = (float*)(ws + 40960);              // 160000
  unsigned*       maxiou = (unsigned*)(ws + 201216);          // 40000
  unsigned short* Whi    = (unsigned short*)(ws + 241664);    // 786432
  unsigned short* Wlo    = (unsigned short*)(ws + 1028096);   // 786432
  unsigned short* XtA_hi = (unsigned short*)(ws + 1814528);   // 5177344
  unsigned short* XtA_lo = (unsigned short*)(ws + 6991872);   // 5177344
  unsigned short* XtB_hi = (unsigned short*)(ws + 12169216);  // 5177344
  unsigned short* XtB_lo = (unsigned short*)(ws + 17346560);  // 5177344
  // Select-path scratch aliases XtB (dead before k_mlp layer 0 writes XtB):
  int*                rnk  = (int*)(ws + 12169216);                 // 160000
  unsigned long long* ck   = (unsigned long long*)(ws + 12329216);  // 86016
  int*                cnt2 = (int*)(ws + 12415232);                 // 43008
  int*                nc   = (int*)(ws + 12458240);                 // 8
  unsigned*           selT = (unsigned*)(ws + 12458304);            // 8

  k_prepW<<<(6 * C_ * C_ + 255) / 256, 256, 0, stream>>>(W, Whi, Wlo);
  k_sel<<<B_, 1024, 0, stream>>>(score, nc, selT);
  k_zero<<<(B_ * CAP_ + 255) / 256, 256, 0, stream>>>(cnt2, B_ * CAP_);
  k_compact<<<dim3((N_ + 255) / 256, B_), 256, 0, stream>>>(score, selT, nc, ck, rnk);
  k_rank2<<<dim3(RT_, RCH_, B_), 256, 0, stream>>>(nc, ck, cnt2);
  k_scatter2<<<dim3(RT_, B_), 256, 0, stream>>>(nc, ck, cnt2, keep_i, out_keep, rnk);
  k_gatherbox<<<(B_ * K_ + 255) / 256, 256, 0, stream>>>(keep_i, box, boxK, maxiou);
  k_iou<<<dim3((K_ + 255) / 256, (K_ + 255) / 256, B_), 256, 0, stream>>>(boxK, maxiou);
  k_gathersplit<<<dim3((N_ + 63) / 64, C_ / 64, B_), 256, 0, stream>>>(rnk, feat, XtA_hi, XtA_lo);

  const unsigned short* xih = XtA_hi; const unsigned short* xil = XtA_lo;
  unsigned short* xoh = XtB_hi;       unsigned short* xol = XtB_lo;
  for (int l = 0; l < 6; ++l) {
    k_mlp<<<dim3(MROWS_ / 128, C_ / 64), 256, 0, stream>>>(
        Whi + (size_t)l * C_ * C_, Wlo + (size_t)l * C_ * C_,
        bias + (size_t)l * C_, xih, xil, xoh, xol);
    const unsigned short* th = xoh; const unsigned short* tl = xol;
    xoh = (unsigned short*)xih; xol = (unsigned short*)xil;
    xih = th; xil = tl;
  }
  // after 6 layers activations are in XtA (xih/xil point at it)

  k_final<<<(M_ + 255) / 256, 256, 0, stream>>>(xih, xil, Wf, bf, maxiou, out_loc);
}